// Round 7
// baseline (189.307 us; speedup 1.0000x reference)
//
#include <hip/hip_runtime.h>
#include <hip/hip_bf16.h>
#include <stdint.h>

// Problem constants
#define T_TOK 2048
#define H_DIM 1024
#define I_DIM 768
#define E_NUM 16
#define K_TOP 4
#define NSLOT 8192          // (token,k) slots
#define PSLOT 12288         // slot capacity padded to 256/expert
#define NT256 48            // 256-row M tiles

typedef short  s16x8 __attribute__((ext_vector_type(8)));
typedef float  f32x4 __attribute__((ext_vector_type(4)));
typedef unsigned short u16x8 __attribute__((ext_vector_type(8)));

#define MEMFENCE asm volatile("" ::: "memory")

__device__ __forceinline__ void gload16(const void* g, void* l) {
  __builtin_amdgcn_global_load_lds(
      (const __attribute__((address_space(1))) uint32_t*)g,
      (__attribute__((address_space(3))) uint32_t*)l, 16, 0, 0);
}

__device__ __forceinline__ unsigned short f2bf(float f) {
  __hip_bfloat16 h = __float2bfloat16(f);
  return *reinterpret_cast<unsigned short*>(&h);
}

// fp32x16 -> two bf16x8 chunks into swizzled 16B slots of LDS row r.
// Contract: phys slot p of row r holds logical slot p ^ ((r>>1)&3).
__device__ __forceinline__ void write_b_row(char* bregion, int r, int half,
                                            f32x4 f0, f32x4 f1, f32x4 f2, f32x4 f3) {
  u16x8 c0, c1;
  c0[0]=f2bf(f0[0]); c0[1]=f2bf(f0[1]); c0[2]=f2bf(f0[2]); c0[3]=f2bf(f0[3]);
  c0[4]=f2bf(f1[0]); c0[5]=f2bf(f1[1]); c0[6]=f2bf(f1[2]); c0[7]=f2bf(f1[3]);
  c1[0]=f2bf(f2[0]); c1[1]=f2bf(f2[1]); c1[2]=f2bf(f2[2]); c1[3]=f2bf(f2[3]);
  c1[4]=f2bf(f3[0]); c1[5]=f2bf(f3[1]); c1[6]=f2bf(f3[2]); c1[7]=f2bf(f3[3]);
  int xr = (r >> 1) & 3;
  char* wb = bregion + r * 64;
  *(u16x8*)(wb + (((2*half + 0) ^ xr) * 16)) = c0;
  *(u16x8*)(wb + (((2*half + 1) ^ xr) * 16)) = c1;
}

// ---------------- fp32 -> bf16 conversion (X only) -------------------------
__global__ __launch_bounds__(256) void cvt_bf16_kernel(
    const float* __restrict__ in, unsigned short* __restrict__ out, int n8) {
  int i = blockIdx.x * 256 + threadIdx.x;
  if (i >= n8) return;
  const float4* p = (const float4*)in;
  float4 a = p[2 * (size_t)i];
  float4 b = p[2 * (size_t)i + 1];
  u16x8 o;
  o[0] = f2bf(a.x); o[1] = f2bf(a.y); o[2] = f2bf(a.z); o[3] = f2bf(a.w);
  o[4] = f2bf(b.x); o[5] = f2bf(b.y); o[6] = f2bf(b.z); o[7] = f2bf(b.w);
  *(u16x8*)(out + (size_t)i * 8) = o;
}

// ---------------- deterministic routing (256-padded experts) ----------------
__global__ __launch_bounds__(256) void route_kernel(
    const int* __restrict__ idx, const float* __restrict__ wts,
    int* __restrict__ slot_tok, float* __restrict__ slot_w,
    int* __restrict__ slot_of, int* __restrict__ tile_expert) {
  __shared__ int cnt[256][16];
  __shared__ int tot[16];
  __shared__ int pb[17];
  int tid = threadIdx.x;

  for (int e = 0; e < 16; ++e) cnt[tid][e] = 0;
  const int s0 = tid * 32;
  for (int i = 0; i < 32; ++i) {
    int e = idx[s0 + i] & 15;
    cnt[tid][e]++;
  }
  __syncthreads();
  if (tid < 16) {
    int run = 0;
    for (int c = 0; c < 256; ++c) { int v = cnt[c][tid]; cnt[c][tid] = run; run += v; }
    tot[tid] = run;
  }
  __syncthreads();
  if (tid == 0) {
    int acc = 0;
    for (int e = 0; e < 16; ++e) { pb[e] = acc; acc += (tot[e] + 255) & ~255; }
    pb[16] = acc;
  }
  __syncthreads();
  for (int p = tid; p < PSLOT; p += 256) { slot_tok[p] = 0; slot_w[p] = 0.0f; }
  if (tid < NT256) {
    int ef = -1;
    for (int e = 0; e < 16; ++e)
      if (tid * 256 >= pb[e] && tid * 256 < pb[e + 1]) ef = e;
    tile_expert[tid] = ef;
  }
  __syncthreads();
  for (int i = 0; i < 32; ++i) {
    int s = s0 + i;
    int e = idx[s] & 15;
    int pos = pb[e] + cnt[tid][e]++;
    slot_tok[pos] = s >> 2;
    slot_w[pos]   = wts[s];
    slot_of[s]    = pos;
  }
}

// Pipeline (both GEMMs), per iter kt. Per-iter vmem = A(4 gload_lds) + B(4 loads).
// Issue order fenced: A(kt+1) then B(kt+3).
//   vmcnt(12) retires B(kt+1) regs AND A(kt)->LDS (induction from prologue).
//   ds_write B(kt+1); lgkmcnt(0); barrier; compute buf[kt&1]; barrier.
// Prologue: A0,B0,B1,B2 (16 ops); vmcnt(8) retires A0+B0; write B0.
// Tail: load indices clamped to NT-1 (writes land in dead buffers).

// ---------------- GEMM1: BM=256 slots, BN=64 dual (gate|up), BK=32 ----------
// 256 thr = 4 waves (2M x 2N); wave tile 128M x 32N per panel. acc 32 f32x4.
__global__ __launch_bounds__(256) void gemm1_kernel(
    const unsigned short* __restrict__ Xbf,       // [2048][1024] bf16
    const float* __restrict__ Wgu,                // [16][1536][1024] fp32
    const int* __restrict__ slot_tok,
    const int* __restrict__ tile_expert,
    unsigned short* __restrict__ hbuf) {          // [PSLOT][768] bf16
  // XCD-chunked remap: 576 blocks, 72/XCD (576%8==0); same-expert tiles same XCD
  int bid  = blockIdx.y * 12 + blockIdx.x;
  int sbid = (bid & 7) * 72 + (bid >> 3);
  int by = sbid / 12, bx = sbid % 12;
  int e = tile_expert[by];
  if (e < 0) return;
  int m0 = by * 256;
  int t = threadIdx.x;
  int lane = t & 63, w = t >> 6;
  int wr = w >> 1, wc = w & 1;
  int l15 = lane & 15, lhi = lane >> 4;

  // per buffer: A 256x64B = 16KB @0, B 128x64B = 8KB @16384; 2 buffers = 48KB
  __shared__ char lds[2 * 24576];
  char* buf0 = lds;
  char* buf1 = lds + 24576;

  // ---- A staging: 4 gload calls, 64 rows each; source col pre-swizzled ----
  int arow = t >> 2;                                  // 0..63 within band
  int aswz = ((t & 3) ^ ((t >> 3) & 3)) * 16;
  const char* gA[4];
#pragma unroll
  for (int c = 0; c < 4; ++c) {
    int tok = slot_tok[m0 + c * 64 + arow];
    gA[c] = (const char*)(Xbf + (size_t)tok * H_DIM) + aswz;
  }

  // ---- B staging (fp32 regs): row = t>>1 (0..127 = 64 gate | 64 up) -------
  int brow = t >> 1;
  int half = t & 1;                                   // 16-float half of 32-k window
  int prow = (brow < 64) ? (bx * 64 + brow) : (768 + bx * 64 + (brow - 64));
  const float* gB = Wgu + ((size_t)e * 1536 + prow) * H_DIM + half * 16;

  int pswz = (lhi ^ ((l15 >> 1) & 3)) * 8;            // read-side slot (shorts)

  f32x4 accg[8][2] = {};
  f32x4 accu[8][2] = {};
  f32x4 s0_0, s0_1, s0_2, s0_3, s1_0, s1_1, s1_2, s1_3;
  f32x4 s2_0, s2_1, s2_2, s2_3, s3_0, s3_1, s3_2, s3_3;

#define NT1 32
#define A_GLOAD1(kt, bufp) do {                               \
    int kk_ = (kt) < NT1 ? (kt) : NT1 - 1;                    \
    size_t ko_ = (size_t)kk_ * 64;                            \
    gload16(gA[0] + ko_, (bufp) + t * 16);                    \
    gload16(gA[1] + ko_, (bufp) + 4096 + t * 16);             \
    gload16(gA[2] + ko_, (bufp) + 8192 + t * 16);             \
    gload16(gA[3] + ko_, (bufp) + 12288 + t * 16);            \
  } while (0)
#define B_LOAD1(v0, v1, v2, v3, kt) do {                      \
    int kk_ = (kt) < NT1 ? (kt) : NT1 - 1;                    \
    const f32x4* p_ = (const f32x4*)(gB + (size_t)kk_ * 32);  \
    v0 = p_[0]; v1 = p_[1]; v2 = p_[2]; v3 = p_[3];           \
  } while (0)

#define G1_COMPUTE(bufp) do {                                                          \
    const short* La = (const short*)(bufp);                                            \
    const short* Lb = (const short*)((bufp) + 16384);                                  \
    s16x8 af[8], bg[2], bu[2];                                                         \
    _Pragma("unroll")                                                                  \
    for (int mi = 0; mi < 8; ++mi)                                                     \
      af[mi] = *(const s16x8*)(La + (wr * 128 + mi * 16 + l15) * 32 + pswz);           \
    _Pragma("unroll")                                                                  \
    for (int ni = 0; ni < 2; ++ni) {                                                   \
      int row = wc * 32 + ni * 16 + l15;                                               \
      bg[ni] = *(const s16x8*)(Lb + row * 32 + pswz);                                  \
      bu[ni] = *(const s16x8*)(Lb + (64 + row) * 32 + pswz);                           \
    }                                                                                  \
    __builtin_amdgcn_s_setprio(1);                                                     \
    _Pragma("unroll")                                                                  \
    for (int mi = 0; mi < 8; ++mi)                                                     \
      _Pragma("unroll")                                                                \
      for (int ni = 0; ni < 2; ++ni) {                                                 \
        accg[mi][ni] = __builtin_amdgcn_mfma_f32_16x16x32_bf16(af[mi], bg[ni], accg[mi][ni], 0, 0, 0); \
        accu[mi][ni] = __builtin_amdgcn_mfma_f32_16x16x32_bf16(af[mi], bu[ni], accu[mi][ni], 0, 0, 0); \
      }                                                                                \
    __builtin_amdgcn_s_setprio(0);                                                     \
  } while (0)

#define ITER1(kt, wv0, wv1, wv2, wv3, lv0, lv1, lv2, lv3) do {  \
    char* cbuf_ = ((kt) & 1) ? buf1 : buf0;                     \
    char* nbuf_ = ((kt) & 1) ? buf0 : buf1;                     \
    MEMFENCE;                                                   \
    A_GLOAD1((kt) + 1, nbuf_);                                  \
    MEMFENCE;                                                   \
    B_LOAD1(lv0, lv1, lv2, lv3, (kt) + 3);                      \
    asm volatile("s_waitcnt vmcnt(12)" ::: "memory");           \
    write_b_row(nbuf_ + 16384, brow, half, wv0, wv1, wv2, wv3); \
    asm volatile("s_waitcnt lgkmcnt(0)" ::: "memory");          \
    __builtin_amdgcn_s_barrier();                               \
    MEMFENCE;                                                   \
    G1_COMPUTE(cbuf_);                                          \
    MEMFENCE;                                                   \
    __builtin_amdgcn_s_barrier();                               \
  } while (0)

  // prologue (fenced: exact issue order A0,B0,B1,B2 = 16 vmem ops)
  A_GLOAD1(0, buf0);
  MEMFENCE;
  B_LOAD1(s0_0, s0_1, s0_2, s0_3, 0);
  MEMFENCE;
  B_LOAD1(s1_0, s1_1, s1_2, s1_3, 1);
  MEMFENCE;
  B_LOAD1(s2_0, s2_1, s2_2, s2_3, 2);
  asm volatile("s_waitcnt vmcnt(8)" ::: "memory");   // retires A0 + B0
  write_b_row(buf0 + 16384, brow, half, s0_0, s0_1, s0_2, s0_3);

  for (int kt = 0; kt < NT1; kt += 4) {
    ITER1(kt + 0, s1_0, s1_1, s1_2, s1_3, s3_0, s3_1, s3_2, s3_3);
    ITER1(kt + 1, s2_0, s2_1, s2_2, s2_3, s0_0, s0_1, s0_2, s0_3);
    ITER1(kt + 2, s3_0, s3_1, s3_2, s3_3, s1_0, s1_1, s1_2, s1_3);
    ITER1(kt + 3, s0_0, s0_1, s0_2, s0_3, s2_0, s2_1, s2_2, s2_3);
  }
#undef ITER1
#undef G1_COMPUTE
#undef B_LOAD1
#undef A_GLOAD1

  // epilogue: h = silu(g)*u ; C layout col=lane&15, row=(lane>>4)*4+q
#pragma unroll
  for (int mi = 0; mi < 8; ++mi) {
#pragma unroll
    for (int ni = 0; ni < 2; ++ni) {
      int col = bx * 64 + wc * 32 + ni * 16 + l15;
#pragma unroll
      for (int q = 0; q < 4; ++q) {
        int m = m0 + wr * 128 + mi * 16 + lhi * 4 + q;
        float g = accg[mi][ni][q];
        float u = accu[mi][ni][q];
        float s = g / (1.0f + __expf(-g));
        hbuf[(size_t)m * I_DIM + col] = f2bf(s * u);
      }
    }
  }
}

// ---------------- GEMM2: BM=256, BN=128, BK=32; y = (h@Wd^T)*w --------------
// 256 thr = 4 waves (2M x 2N); wave tile 128M x 64N. acc 32 f32x4.
__global__ __launch_bounds__(256) void gemm2_kernel(
    const unsigned short* __restrict__ hbuf,      // [PSLOT][768] bf16
    const float* __restrict__ Wd,                 // [16][1024][768] fp32
    const float* __restrict__ slot_w,
    const int* __restrict__ tile_expert,
    float* __restrict__ y) {                      // [PSLOT][1024] fp32
  // XCD-chunked remap: 384 blocks, 48/XCD
  int bid  = blockIdx.y * 8 + blockIdx.x;
  int sbid = (bid & 7) * 48 + (bid >> 3);
  int by   = sbid >> 3;
  int bx   = sbid & 7;
  int e = tile_expert[by];
  if (e < 0) return;
  int m0 = by * 256;
  int t = threadIdx.x;
  int lane = t & 63, w = t >> 6;
  int wr = w >> 1, wc = w & 1;
  int l15 = lane & 15, lhi = lane >> 4;

  __shared__ char lds[2 * 24576];
  char* buf0 = lds;
  char* buf1 = lds + 24576;

  int arow = t >> 2;
  int aswz = ((t & 3) ^ ((t >> 3) & 3)) * 16;
  const char* gA[4];
#pragma unroll
  for (int c = 0; c < 4; ++c)
    gA[c] = (const char*)(hbuf + (size_t)(m0 + c * 64 + arow) * I_DIM) + aswz;

  int brow = t >> 1;
  int half = t & 1;
  const float* gB = Wd + ((size_t)e * 1024 + bx * 128 + brow) * I_DIM + half * 16;

  int pswz = (lhi ^ ((l15 >> 1) & 3)) * 8;

  f32x4 acc[8][4] = {};
  f32x4 s0_0, s0_1, s0_2, s0_3, s1_0, s1_1, s1_2, s1_3;
  f32x4 s2_0, s2_1, s2_2, s2_3, s3_0, s3_1, s3_2, s3_3;

#define NT2 24
#define A_GLOAD2(kt, bufp) do {                               \
    int kk_ = (kt) < NT2 ? (kt) : NT2 - 1;                    \
    size_t ko_ = (size_t)kk_ * 64;                            \
    gload16(gA[0] + ko_, (bufp) + t * 16);                    \
    gload16(gA[1] + ko_, (bufp) + 4096 + t * 16);             \
    gload16(gA[2] + ko_, (bufp) + 8192 + t * 16);             \
    gload16(gA[3] + ko_, (bufp) + 12288 + t * 16);            \
  } while (0)
#define B_LOAD2(v0, v1, v2, v3, kt) do {                      \
    int kk_ = (kt) < NT2 ? (kt) : NT2 - 1;                    \
    const f32x4* p_ = (const f32x4*)(gB + (size_t)kk_ * 32);  \
    v0 = p_[0]; v1 = p_[1]; v2 = p_[2]; v3 = p_[3];           \
  } while (0)

#define G2_COMPUTE(bufp) do {                                                          \
    const short* La = (const short*)(bufp);                                            \
    const short* Lb = (const short*)((bufp) + 16384);                                  \
    s16x8 af[8], bf[4];                                                                \
    _Pragma("unroll")                                                                  \
    for (int mi = 0; mi < 8; ++mi)                                                     \
      af[mi] = *(const s16x8*)(La + (wr * 128 + mi * 16 + l15) * 32 + pswz);           \
    _Pragma("unroll")                                                                  \
    for (int ni = 0; ni < 4; ++ni)                                                     \
      bf[ni] = *(const s16x8*)(Lb + (wc * 64 + ni * 16 + l15) * 32 + pswz);            \
    __builtin_amdgcn_s_setprio(1);                                                     \
    _Pragma("unroll")                                                                  \
    for (int mi = 0; mi < 8; ++mi)                                                     \
      _Pragma("unroll")                                                                \
      for (int ni = 0; ni < 4; ++ni)                                                   \
        acc[mi][ni] = __builtin_amdgcn_mfma_f32_16x16x32_bf16(af[mi], bf[ni], acc[mi][ni], 0, 0, 0); \
    __builtin_amdgcn_s_setprio(0);                                                     \
  } while (0)

#define ITER2(kt, wv0, wv1, wv2, wv3, lv0, lv1, lv2, lv3) do {  \
    char* cbuf_ = ((kt) & 1) ? buf1 : buf0;                     \
    char* nbuf_ = ((kt) & 1) ? buf0 : buf1;                     \
    MEMFENCE;                                                   \
    A_GLOAD2((kt) + 1, nbuf_);                                  \
    MEMFENCE;                                                   \
    B_LOAD2(lv0, lv1, lv2, lv3, (kt) + 3);                      \
    asm volatile("s_waitcnt vmcnt(12)" ::: "memory");           \
    write_b_row(nbuf_ + 16384, brow, half, wv0, wv1, wv2, wv3); \
    asm volatile("s_waitcnt lgkmcnt(0)" ::: "memory");          \
    __builtin_amdgcn_s_barrier();                               \
    MEMFENCE;                                                   \
    G2_COMPUTE(cbuf_);                                          \
    MEMFENCE;                                                   \
    __builtin_amdgcn_s_barrier();                               \
  } while (0)

  A_GLOAD2(0, buf0);
  MEMFENCE;
  B_LOAD2(s0_0, s0_1, s0_2, s0_3, 0);
  MEMFENCE;
  B_LOAD2(s1_0, s1_1, s1_2, s1_3, 1);
  MEMFENCE;
  B_LOAD2(s2_0, s2_1, s2_2, s2_3, 2);
  asm volatile("s_waitcnt vmcnt(8)" ::: "memory");
  write_b_row(buf0 + 16384, brow, half, s0_0, s0_1, s0_2, s0_3);

  for (int kt = 0; kt < NT2; kt += 4) {
    ITER2(kt + 0, s1_0, s1_1, s1_2, s1_3, s3_0, s3_1, s3_2, s3_3);
    ITER2(kt + 1, s2_0, s2_1, s2_2, s2_3, s0_0, s0_1, s0_2, s0_3);
    ITER2(kt + 2, s3_0, s3_1, s3_2, s3_3, s1_0, s1_1, s1_2, s1_3);
    ITER2(kt + 3, s0_0, s0_1, s0_2, s0_3, s2_0, s2_1, s2_2, s2_3);
  }
#undef ITER2
#undef G2_COMPUTE
#undef B_LOAD2
#undef A_GLOAD2

  // epilogue: y = acc * w_slot (padding rows: w=0 -> 0; never read by combine)
#pragma unroll
  for (int mi = 0; mi < 8; ++mi) {
#pragma unroll
    for (int q = 0; q < 4; ++q) {
      int m = m0 + wr * 128 + mi * 16 + lhi * 4 + q;
      float wgt = slot_w[m];
      float* orow = y + (size_t)m * H_DIM + bx * 128 + wc * 64 + l15;
#pragma unroll
      for (int ni = 0; ni < 4; ++ni)
        orow[ni * 16] = acc[mi][ni][q] * wgt;
    }
  }
}

// ---------------- combine: out[t] = sum_k y[slot_of[t,k]] -------------------
__global__ __launch_bounds__(256) void combine_kernel(
    const float* __restrict__ y, const int* __restrict__ slot_of,
    float* __restrict__ out) {
  int t = blockIdx.x;
  int c = threadIdx.x * 4;
  int s0 = slot_of[t * 4 + 0], s1 = slot_of[t * 4 + 1];
  int s2 = slot_of[t * 4 + 2], s3 = slot_of[t * 4 + 3];
  f32x4 v0 = *(const f32x4*)(y + (size_t)s0 * H_DIM + c);
  f32x4 v1 = *(const f32x4*)(y + (size_t)s1 * H_DIM + c);
  f32x4 v2 = *(const f32x4*)(y + (size_t)s2 * H_DIM + c);
  f32x4 v3 = *(const f32x4*)(y + (size_t)s3 * H_DIM + c);
  f32x4 r = (v0 + v1) + (v2 + v3);
  *(f32x4*)(out + (size_t)t * H_DIM + c) = r;
}

// ---------------- launch ----------------
extern "C" void kernel_launch(void* const* d_in, const int* in_sizes, int n_in,
                              void* d_out, int out_size, void* d_ws, size_t ws_size,
                              hipStream_t stream) {
  const float* hs       = (const float*)d_in[0];
  const int*   topk_idx = (const int*)d_in[1];
  const float* topk_w   = (const float*)d_in[2];
  const float* w_gu     = (const float*)d_in[3];   // [16][1536][1024]
  const float* w_d      = (const float*)d_in[4];   // [16][1024][768]
  float* out = (float*)d_out;

  char* ws = (char*)d_ws;
  unsigned short* Xbf  = (unsigned short*)(ws);                 //  4,194,304
  unsigned short* hbuf = (unsigned short*)(ws + 4194304);       // 18,874,368
  float*          y    = (float*)(ws + 23068672);               // 50,331,648
  int*   slot_tok    = (int*)(ws + 73400320);                   //     49,152
  float* slot_w      = (float*)(ws + 73449472);                 //     49,152
  int*   slot_of     = (int*)(ws + 73498624);                   //     32,768
  int*   tile_expert = (int*)(ws + 73531392);                   //        256
  // total ~73.5 MB

  cvt_bf16_kernel<<<1024, 256, 0, stream>>>(hs, Xbf, T_TOK * H_DIM / 8);
  route_kernel<<<1, 256, 0, stream>>>(topk_idx, topk_w, slot_tok, slot_w,
                                      slot_of, tile_expert);

  gemm1_kernel<<<dim3(12, NT256), 256, 0, stream>>>(Xbf, w_gu, slot_tok, tile_expert, hbuf);
  gemm2_kernel<<<dim3(8, NT256), 256, 0, stream>>>(hbuf, w_d, slot_w, tile_expert, y);
  combine_kernel<<<T_TOK, 256, 0, stream>>>(y, slot_of, out);
}

// Round 8
// 127.200 us; speedup vs baseline: 1.4883x; 1.4883x over previous
//
#include <hip/hip_runtime.h>
#include <hip/hip_bf16.h>
#include <stdint.h>

// Problem constants
#define T_TOK 2048
#define H_DIM 1024
#define I_DIM 768
#define E_NUM 16
#define K_TOP 4
#define NSLOT (T_TOK * K_TOP)   // 8192 (token,k) slots
#define PSLOT 10240             // slot capacity padded to 128/expert
#define NTILE 80                // PSLOT / 128 M-tiles

typedef short  s16x8 __attribute__((ext_vector_type(8)));
typedef float  f32x4 __attribute__((ext_vector_type(4)));
typedef unsigned short u16x8 __attribute__((ext_vector_type(8)));

#define MEMFENCE asm volatile("" ::: "memory")

__device__ __forceinline__ void gload16(const void* g, void* l) {
  __builtin_amdgcn_global_load_lds(
      (const __attribute__((address_space(1))) uint32_t*)g,
      (__attribute__((address_space(3))) uint32_t*)l, 16, 0, 0);
}

__device__ __forceinline__ unsigned short f2bf(float f) {
  __hip_bfloat16 h = __float2bfloat16(f);
  return *reinterpret_cast<unsigned short*>(&h);
}

// fp32x16 -> two bf16x8 chunks into swizzled 16B slots of LDS row r (gemm2).
__device__ __forceinline__ void write_b_row(char* bregion, int r, int half,
                                            f32x4 f0, f32x4 f1, f32x4 f2, f32x4 f3) {
  u16x8 c0, c1;
  c0[0]=f2bf(f0[0]); c0[1]=f2bf(f0[1]); c0[2]=f2bf(f0[2]); c0[3]=f2bf(f0[3]);
  c0[4]=f2bf(f1[0]); c0[5]=f2bf(f1[1]); c0[6]=f2bf(f1[2]); c0[7]=f2bf(f1[3]);
  c1[0]=f2bf(f2[0]); c1[1]=f2bf(f2[1]); c1[2]=f2bf(f2[2]); c1[3]=f2bf(f2[3]);
  c1[4]=f2bf(f3[0]); c1[5]=f2bf(f3[1]); c1[6]=f2bf(f3[2]); c1[7]=f2bf(f3[3]);
  int xr = (r >> 1) & 3;
  char* wb = bregion + r * 64;
  *(u16x8*)(wb + (((2*half + 0) ^ xr) * 16)) = c0;
  *(u16x8*)(wb + (((2*half + 1) ^ xr) * 16)) = c1;
}

// ---------------- fp32 -> bf16 conversion (X only) -------------------------
__global__ __launch_bounds__(256) void cvt_bf16_kernel(
    const float* __restrict__ in, unsigned short* __restrict__ out, int n8) {
  int i = blockIdx.x * 256 + threadIdx.x;
  if (i >= n8) return;
  const float4* p = (const float4*)in;
  float4 a = p[2 * (size_t)i];
  float4 b = p[2 * (size_t)i + 1];
  u16x8 o;
  o[0] = f2bf(a.x); o[1] = f2bf(a.y); o[2] = f2bf(a.z); o[3] = f2bf(a.w);
  o[4] = f2bf(b.x); o[5] = f2bf(b.y); o[6] = f2bf(b.z); o[7] = f2bf(b.w);
  *(u16x8*)(out + (size_t)i * 8) = o;
}

// ---------------- deterministic routing: stable counting sort ----------------
__global__ __launch_bounds__(256) void route_kernel(
    const int* __restrict__ idx, const float* __restrict__ wts,
    int* __restrict__ slot_tok, float* __restrict__ slot_w,
    int* __restrict__ slot_of, int* __restrict__ tile_expert) {
  __shared__ int cnt[256][16];
  __shared__ int tot[16];
  __shared__ int pb[17];
  int tid = threadIdx.x;

  for (int e = 0; e < 16; ++e) cnt[tid][e] = 0;
  const int s0 = tid * 32;
  for (int i = 0; i < 32; ++i) {
    int e = idx[s0 + i] & 15;
    cnt[tid][e]++;
  }
  __syncthreads();
  if (tid < 16) {
    int run = 0;
    for (int c = 0; c < 256; ++c) { int v = cnt[c][tid]; cnt[c][tid] = run; run += v; }
    tot[tid] = run;
  }
  __syncthreads();
  if (tid == 0) {
    int acc = 0;
    for (int e = 0; e < 16; ++e) { pb[e] = acc; acc += (tot[e] + 127) & ~127; }
    pb[16] = acc;
  }
  __syncthreads();
  for (int p = tid; p < PSLOT; p += 256) { slot_tok[p] = 0; slot_w[p] = 0.0f; }
  if (tid < NTILE) {
    int ef = -1;
    for (int e = 0; e < 16; ++e)
      if (tid * 128 >= pb[e] && tid * 128 < pb[e + 1]) ef = e;
    tile_expert[tid] = ef;
  }
  __syncthreads();
  for (int i = 0; i < 32; ++i) {
    int s = s0 + i;
    int e = idx[s] & 15;
    int pos = pb[e] + cnt[tid][e]++;
    slot_tok[pos] = s >> 2;
    slot_w[pos]   = wts[s];
    slot_of[s]    = pos;
  }
}

// ---------------- GEMM1: gu = X_slots @ Wgu^T, fused silu(g)*u -> h bf16 ----
// BM=128, BN=64 dual (gate|up), BK=32. ALL staging via global_load_lds:
// A bf16 (2 ops), B raw fp32 (4 ops); bf16 cvt happens at LDS-read time.
// 2-deep counted-vmcnt(6) double buffer (R2-proven skeleton).
// LDS/buf: A 8KB @0 (128 rows x 64B, chunk swz q^((r>>1)&3)),
//          B 16KB @8192 (128 rows x 128B fp32, chunk swz q^(r&7)).
__global__ __launch_bounds__(256) void gemm1_kernel(
    const unsigned short* __restrict__ Xbf,       // [2048][1024] bf16
    const float* __restrict__ Wgu,                // [16][1536][1024] fp32
    const int* __restrict__ slot_tok,
    const int* __restrict__ tile_expert,
    unsigned short* __restrict__ hbuf) {          // [PSLOT][768] bf16
  // XCD-chunked remap: 960 blocks, 120/XCD (bijective)
  int bid  = blockIdx.y * 12 + blockIdx.x;
  int sbid = (bid & 7) * 120 + (bid >> 3);
  int by   = sbid / 12;
  int bx   = sbid % 12;
  int e = tile_expert[by];
  if (e < 0) return;
  int m0 = by * 128;
  int t = threadIdx.x;
  int lane = t & 63, w = t >> 6;
  int wr = w >> 1, wc = w & 1;
  int l15 = lane & 15, lhi = lane >> 4;

  __shared__ char lds[2 * 24576];
  char* buf0 = lds;
  char* buf1 = lds + 24576;

  // ---- A staging (2 gload16, source col pre-swizzled) ----
  int arow = t >> 2;
  int aswz = ((t & 3) ^ ((t >> 3) & 3)) * 16;
  int tok0 = slot_tok[m0 + arow];
  int tok1 = slot_tok[m0 + 64 + arow];
  const char* gA0 = (const char*)(Xbf + (size_t)tok0 * H_DIM) + aswz;
  const char* gA1 = (const char*)(Xbf + (size_t)tok1 * H_DIM) + aswz;

  // ---- B staging (4 gload16, fp32; rows 0..63 gate, 64..127 up) ----
  const char* gBs[4];
#pragma unroll
  for (int c = 0; c < 4; ++c) {
    int r = c * 32 + (t >> 3);
    int prow = (r < 64) ? (bx * 64 + r) : (768 + bx * 64 + (r - 64));
    int q = (t & 7) ^ (r & 7);            // source chunk pre-swizzle (involution)
    gBs[c] = (const char*)(Wgu + ((size_t)e * 1536 + prow) * H_DIM) + q * 16;
  }

  int pswz = (lhi ^ ((l15 >> 1) & 3)) * 8;   // A read-side slot (shorts)

  f32x4 accg[4][2] = {};
  f32x4 accu[4][2] = {};

#define NT1 32
#define G1_STAGE(bufp, kt) do {                               \
    size_t ao = (size_t)(kt) * 64;                            \
    size_t bo = (size_t)(kt) * 128;                           \
    gload16(gA0 + ao, (bufp) + t * 16);                       \
    gload16(gA1 + ao, (bufp) + 4096 + t * 16);                \
    gload16(gBs[0] + bo, (bufp) + 8192 + t * 16);             \
    gload16(gBs[1] + bo, (bufp) + 12288 + t * 16);            \
    gload16(gBs[2] + bo, (bufp) + 16384 + t * 16);            \
    gload16(gBs[3] + bo, (bufp) + 20480 + t * 16);            \
  } while (0)

  // read one B frag (row rb) from fp32 LDS, cvt -> s16x8
#define B_FRAG(dst, cb, rb) do {                                              \
    const char* base_ = (cb) + 8192 + (rb) * 128;                             \
    f32x4 x0_ = *(const f32x4*)(base_ + (((2*lhi    ) ^ ((rb) & 7)) * 16));   \
    f32x4 x1_ = *(const f32x4*)(base_ + (((2*lhi + 1) ^ ((rb) & 7)) * 16));   \
    s16x8 o_;                                                                 \
    o_[0]=(short)f2bf(x0_[0]); o_[1]=(short)f2bf(x0_[1]);                     \
    o_[2]=(short)f2bf(x0_[2]); o_[3]=(short)f2bf(x0_[3]);                     \
    o_[4]=(short)f2bf(x1_[0]); o_[5]=(short)f2bf(x1_[1]);                     \
    o_[6]=(short)f2bf(x1_[2]); o_[7]=(short)f2bf(x1_[3]);                     \
    dst = o_;                                                                 \
  } while (0)

#define G1_COMPUTE(cb) do {                                                            \
    const short* La = (const short*)(cb);                                              \
    s16x8 af[4], bg[2], bu[2];                                                         \
    _Pragma("unroll")                                                                  \
    for (int mi = 0; mi < 4; ++mi)                                                     \
      af[mi] = *(const s16x8*)(La + (wr * 64 + mi * 16 + l15) * 32 + pswz);            \
    _Pragma("unroll")                                                                  \
    for (int ni = 0; ni < 2; ++ni) {                                                   \
      int rbg = wc * 32 + ni * 16 + l15;                                               \
      B_FRAG(bg[ni], (cb), rbg);                                                       \
      B_FRAG(bu[ni], (cb), rbg + 64);                                                  \
    }                                                                                  \
    __builtin_amdgcn_s_setprio(1);                                                     \
    _Pragma("unroll")                                                                  \
    for (int mi = 0; mi < 4; ++mi)                                                     \
      _Pragma("unroll")                                                                \
      for (int ni = 0; ni < 2; ++ni) {                                                 \
        accg[mi][ni] = __builtin_amdgcn_mfma_f32_16x16x32_bf16(af[mi], bg[ni], accg[mi][ni], 0, 0, 0); \
        accu[mi][ni] = __builtin_amdgcn_mfma_f32_16x16x32_bf16(af[mi], bu[ni], accu[mi][ni], 0, 0, 0); \
      }                                                                                \
    __builtin_amdgcn_s_setprio(0);                                                     \
  } while (0)

  G1_STAGE(buf0, 0);
  int cur = 0;
  for (int kt = 0; kt < NT1; ++kt) {
    char* cbuf = cur ? buf1 : buf0;
    char* nbuf = cur ? buf0 : buf1;
    if (kt + 1 < NT1) {
      MEMFENCE;
      G1_STAGE(nbuf, kt + 1);
      asm volatile("s_waitcnt vmcnt(6)" ::: "memory");
    } else {
      asm volatile("s_waitcnt vmcnt(0)" ::: "memory");
    }
    __builtin_amdgcn_s_barrier();
    MEMFENCE;
    G1_COMPUTE(cbuf);
    MEMFENCE;
    __builtin_amdgcn_s_barrier();
    cur ^= 1;
  }
#undef G1_STAGE
#undef G1_COMPUTE
#undef B_FRAG

  // epilogue: h = silu(g)*u ; C layout col=lane&15, row=(lane>>4)*4+q
#pragma unroll
  for (int mi = 0; mi < 4; ++mi) {
#pragma unroll
    for (int ni = 0; ni < 2; ++ni) {
      int col = bx * 64 + wc * 32 + ni * 16 + l15;
#pragma unroll
      for (int q = 0; q < 4; ++q) {
        int m = m0 + wr * 64 + mi * 16 + lhi * 4 + q;
        float g = accg[mi][ni][q];
        float u = accu[mi][ni][q];
        float s = g / (1.0f + __expf(-g));
        hbuf[(size_t)m * I_DIM + col] = f2bf(s * u);
      }
    }
  }
}

// ---------------- GEMM2 (R5-proven): y = (h@Wd^T)*w, plain stores -----------
__global__ __launch_bounds__(256) void gemm2_kernel(
    const unsigned short* __restrict__ hbuf,      // [PSLOT][768] bf16
    const float* __restrict__ Wd,                 // [16][1024][768] fp32
    const int* __restrict__ slot_tok,
    const float* __restrict__ slot_w,
    const int* __restrict__ tile_expert,
    float* __restrict__ y) {                      // [PSLOT][1024] fp32
  // XCD-chunked remap: 640 blocks, 80/XCD
  int bid  = blockIdx.y * 8 + blockIdx.x;
  int sbid = (bid & 7) * 80 + (bid >> 3);
  int by   = sbid >> 3;
  int bx   = sbid & 7;
  int e = tile_expert[by];
  if (e < 0) return;
  int m0 = by * 128;
  int tid = threadIdx.x;
  int lane = tid & 63, w = tid >> 6;
  int wr = w >> 1, wc = w & 1;

  __shared__ short lds[2 * 8192];
  char* buf0 = (char*)lds;
  char* buf1 = buf0 + 16384;

  int srow = tid >> 2;
  int swzc = ((tid & 3) ^ ((tid >> 3) & 3)) * 16;
  const char* gA0 = (const char*)(hbuf + (size_t)(m0 + srow) * I_DIM) + swzc;
  const char* gA1 = (const char*)(hbuf + (size_t)(m0 + 64 + srow) * I_DIM) + swzc;

  int brow = tid >> 1;
  int half = tid & 1;
  const float* gB = Wd + ((size_t)e * 1024 + bx * 128 + brow) * I_DIM + half * 16;

  int pswz = ((lane >> 4) ^ (((lane & 15) >> 1) & 3)) * 8;

  f32x4 acc[4][4] = {};
  f32x4 s0_0, s0_1, s0_2, s0_3, s1_0, s1_1, s1_2, s1_3;
  f32x4 s2_0, s2_1, s2_2, s2_3, s3_0, s3_1, s3_2, s3_3;

#define NT2 24
#define A_GLOAD2(kt, bufp) do {                               \
    int kk_ = (kt) < NT2 ? (kt) : NT2 - 1;                    \
    int ko_ = kk_ * 64;                                       \
    gload16(gA0 + ko_, (bufp) + tid * 16);                    \
    gload16(gA1 + ko_, (bufp) + 4096 + tid * 16);             \
  } while (0)
#define B_LOAD2(v0, v1, v2, v3, kt) do {                      \
    int kk_ = (kt) < NT2 ? (kt) : NT2 - 1;                    \
    const f32x4* p_ = (const f32x4*)(gB + (size_t)kk_ * 32);  \
    v0 = p_[0]; v1 = p_[1]; v2 = p_[2]; v3 = p_[3];           \
  } while (0)

#define G2_COMPUTE(bufp) do {                                                          \
    const short* La = (const short*)(bufp);                                            \
    s16x8 af[4], bf[4];                                                                \
    _Pragma("unroll")                                                                  \
    for (int mi = 0; mi < 4; ++mi)                                                     \
      af[mi] = *(const s16x8*)(La + (wr * 64 + mi * 16 + (lane & 15)) * 32 + pswz);    \
    _Pragma("unroll")                                                                  \
    for (int ni = 0; ni < 4; ++ni)                                                     \
      bf[ni] = *(const s16x8*)(La + 4096 + (wc * 64 + ni * 16 + (lane & 15)) * 32 + pswz); \
    _Pragma("unroll")                                                                  \
    for (int mi = 0; mi < 4; ++mi)                                                     \
      _Pragma("unroll")                                                                \
      for (int ni = 0; ni < 4; ++ni)                                                   \
        acc[mi][ni] = __builtin_amdgcn_mfma_f32_16x16x32_bf16(af[mi], bf[ni], acc[mi][ni], 0, 0, 0); \
  } while (0)

#define ITER2(kt, wv0, wv1, wv2, wv3, lv0, lv1, lv2, lv3) do {  \
    char* cbuf_ = ((kt) & 1) ? buf1 : buf0;                     \
    char* nbuf_ = ((kt) & 1) ? buf0 : buf1;                     \
    MEMFENCE;                                                   \
    A_GLOAD2((kt) + 1, nbuf_);                                  \
    MEMFENCE;                                                   \
    B_LOAD2(lv0, lv1, lv2, lv3, (kt) + 3);                      \
    asm volatile("s_waitcnt vmcnt(10)" ::: "memory");           \
    write_b_row(nbuf_ + 8192, brow, half, wv0, wv1, wv2, wv3);  \
    asm volatile("s_waitcnt lgkmcnt(0)" ::: "memory");          \
    __builtin_amdgcn_s_barrier();                               \
    MEMFENCE;                                                   \
    G2_COMPUTE(cbuf_);                                          \
    MEMFENCE;                                                   \
    __builtin_amdgcn_s_barrier();                               \
  } while (0)

  A_GLOAD2(0, buf0);
  MEMFENCE;
  B_LOAD2(s0_0, s0_1, s0_2, s0_3, 0);
  MEMFENCE;
  B_LOAD2(s1_0, s1_1, s1_2, s1_3, 1);
  MEMFENCE;
  B_LOAD2(s2_0, s2_1, s2_2, s2_3, 2);
  asm volatile("s_waitcnt vmcnt(8)" ::: "memory");
  write_b_row(buf0 + 8192, brow, half, s0_0, s0_1, s0_2, s0_3);

  for (int kt = 0; kt < NT2; kt += 4) {
    ITER2(kt + 0, s1_0, s1_1, s1_2, s1_3, s3_0, s3_1, s3_2, s3_3);
    ITER2(kt + 1, s2_0, s2_1, s2_2, s2_3, s0_0, s0_1, s0_2, s0_3);
    ITER2(kt + 2, s3_0, s3_1, s3_2, s3_3, s1_0, s1_1, s1_2, s1_3);
    ITER2(kt + 3, s0_0, s0_1, s0_2, s0_3, s2_0, s2_1, s2_2, s2_3);
  }
#undef ITER2
#undef G2_COMPUTE
#undef B_LOAD2
#undef A_GLOAD2

#pragma unroll
  for (int mi = 0; mi < 4; ++mi) {
#pragma unroll
    for (int q = 0; q < 4; ++q) {
      int m = m0 + wr * 64 + mi * 16 + (lane >> 4) * 4 + q;
      float wgt = slot_w[m];
      float* orow = y + (size_t)m * H_DIM + bx * 128 + wc * 64 + (lane & 15);
#pragma unroll
      for (int ni = 0; ni < 4; ++ni)
        orow[ni * 16] = acc[mi][ni][q] * wgt;
    }
  }
}

// ---------------- combine: out[t] = sum_k y[slot_of[t,k]] -------------------
__global__ __launch_bounds__(256) void combine_kernel(
    const float* __restrict__ y, const int* __restrict__ slot_of,
    float* __restrict__ out) {
  int t = blockIdx.x;
  int c = threadIdx.x * 4;
  int s0 = slot_of[t * 4 + 0], s1 = slot_of[t * 4 + 1];
  int s2 = slot_of[t * 4 + 2], s3 = slot_of[t * 4 + 3];
  f32x4 v0 = *(const f32x4*)(y + (size_t)s0 * H_DIM + c);
  f32x4 v1 = *(const f32x4*)(y + (size_t)s1 * H_DIM + c);
  f32x4 v2 = *(const f32x4*)(y + (size_t)s2 * H_DIM + c);
  f32x4 v3 = *(const f32x4*)(y + (size_t)s3 * H_DIM + c);
  f32x4 r = (v0 + v1) + (v2 + v3);
  *(f32x4*)(out + (size_t)t * H_DIM + c) = r;
}

// ---------------- launch ----------------
extern "C" void kernel_launch(void* const* d_in, const int* in_sizes, int n_in,
                              void* d_out, int out_size, void* d_ws, size_t ws_size,
                              hipStream_t stream) {
  const float* hs       = (const float*)d_in[0];
  const int*   topk_idx = (const int*)d_in[1];
  const float* topk_w   = (const float*)d_in[2];
  const float* w_gu     = (const float*)d_in[3];   // [16][1536][1024]
  const float* w_d      = (const float*)d_in[4];   // [16][1024][768]
  float* out = (float*)d_out;

  char* ws = (char*)d_ws;
  unsigned short* Xbf  = (unsigned short*)(ws);                 //  4,194,304
  unsigned short* hbuf = (unsigned short*)(ws + 4194304);       // 15,728,640
  float*          y    = (float*)(ws + 19922944);               // 41,943,040
  int*   slot_tok    = (int*)(ws + 61865984);
  float* slot_w      = (float*)(ws + 61906944);
  int*   slot_of     = (int*)(ws + 61947904);
  int*   tile_expert = (int*)(ws + 61980672);
  // total ~62 MB

  cvt_bf16_kernel<<<1024, 256, 0, stream>>>(hs, Xbf, T_TOK * H_DIM / 8);
  route_kernel<<<1, 256, 0, stream>>>(topk_idx, topk_w, slot_tok, slot_w,
                                      slot_of, tile_expert);

  gemm1_kernel<<<dim3(12, NTILE), 256, 0, stream>>>(Xbf, w_gu, slot_tok, tile_expert, hbuf);
  gemm2_kernel<<<dim3(8, NTILE), 256, 0, stream>>>(hbuf, w_d, slot_tok, slot_w, tile_expert, y);
  combine_kernel<<<T_TOK, 256, 0, stream>>>(y, slot_of, out);
}